// Round 18
// baseline (29.770 us; speedup 1.0000x reference)
//
#include <hip/hip_runtime.h>

// VQ codebook search via bf16 MFMA — argmin + LINEAR-write scatter.
// latents: [32, 64, 64, 64] = [b, d, h, w] fp32
// emb:     [512, 64] fp32
// out:     8388608 floats quantized (b,d,h,w) + 1 float vq_loss
//
// K1 (unchanged from R17, known-good): 512 blocks x 512 thr, 256 px/block.
//   A = bf16(E) PINNED in VGPRs (opaque asm def stops rematerialization —
//   R8/R9 3x bug). Split staging keeps liveness under the 85-reg cap.
//   score' = 16 - 2 x.e (e2 dropped: |e2| <= 2.4e-4 << bf16 score noise);
//   key = (float_bits & ~511) | code; min-tree + LDS atomicMin.
//   Outputs inds[b][hw] u16 + per-block loss partials.
// K2 (NEW): block = (b, 8-d-group) -> writes out[b][d0..d0+8][0..4096) =
//   128KB FULLY LINEAR per block (structurally identical to the 6.5TB/s
//   fill kernel). Thread owns 8px x 8d (two 4-px groups); emb gathers are
//   L2-hot; 16 nontemporal f32x4 stores tile the region. Block 256 reduces
//   the loss partials (finalize fused).
//
// ws layout: [0..512) float partials; byte 4096+: inds u16[NPIX] (256KB).

typedef short  short8v __attribute__((ext_vector_type(8)));
typedef float  f32x4   __attribute__((ext_vector_type(4)));
typedef unsigned int uint4v __attribute__((ext_vector_type(4)));

constexpr int K = 512;
constexpr int D = 64;
constexpr int HW = 4096;
constexpr int NPIX = 32 * HW;
constexpr long long NELEM = (long long)NPIX * D;
constexpr int PXT = 256;                  // pixels per K1 block
constexpr int NBLK = NPIX / PXT;          // 512 K1 blocks

__device__ inline unsigned cvtpk(float lo, float hi) {   // 2x f32 -> packed bf16 (RNE)
    unsigned r;
    asm("v_cvt_pk_bf16_f32 %0, %1, %2" : "=v"(r) : "v"(lo), "v"(hi));
    return r;
}
__device__ inline unsigned umin32(unsigned a, unsigned b) { return a < b ? a : b; }

// ---- K1: argmin (pure read stream). Unchanged from R17. ----
__global__ __launch_bounds__(512, 6) void vq_argmin(const float* __restrict__ latents,
                                                    const float* __restrict__ emb,
                                                    unsigned short* __restrict__ ginds,
                                                    float* __restrict__ partials) {
    __shared__ unsigned short xbf[PXT * D];      // 32KB bf16(-2x) px-major, swizzled
    __shared__ unsigned int   kred[PXT];         // 1KB block-wide best keys
    __shared__ float          wsum[8], ssum[4];

    const int t    = threadIdx.x;
    const int lane = t & 63, w = t >> 6;         // 8 waves
    const int r15  = lane & 15, g = lane >> 4;
    const int tile = blockIdx.x;
    const int b    = tile >> 4, hw0 = (tile & 15) * PXT;
    const int px0  = (t & 63) * 4;               // 4 px per thread
    const int dh   = t >> 6;                     // 8 d per thread
    const int d0   = dh * 8;

    const float* xg = latents + ((size_t)b * D + d0) * HW + hw0 + px0;
    char* xc = reinterpret_cast<char*>(xbf);
    float x2 = 0.f;

    // ---- stage+pack batch 1 (d rows 0..3): 1KB-contiguous loads, b64 writes.
    {
        f32x4 u0 = *reinterpret_cast<const f32x4*>(xg);
        f32x4 u1 = *reinterpret_cast<const f32x4*>(xg + (size_t)HW);
        f32x4 u2 = *reinterpret_cast<const f32x4*>(xg + 2 * (size_t)HW);
        f32x4 u3 = *reinterpret_cast<const f32x4*>(xg + 3 * (size_t)HW);
        #pragma unroll
        for (int j = 0; j < 4; ++j) {
            int px = px0 + j;
            uint2 pk = {cvtpk(-2.f * u0[j], -2.f * u1[j]),
                        cvtpk(-2.f * u2[j], -2.f * u3[j])};
            int byte = px * 128 + ((dh ^ ((px >> 1) & 7)) << 4);
            *reinterpret_cast<uint2*>(xc + byte) = pk;   // first 8B of the chunk
        }
        #pragma unroll
        for (int j = 0; j < 4; ++j) {
            x2 = fmaf(u0[j], u0[j], x2); x2 = fmaf(u1[j], u1[j], x2);
            x2 = fmaf(u2[j], u2[j], x2); x2 = fmaf(u3[j], u3[j], x2);
        }
    }
    // ---- stage+pack batch 2 (d rows 4..7): second 8B of each chunk.
    {
        f32x4 u0 = *reinterpret_cast<const f32x4*>(xg + 4 * (size_t)HW);
        f32x4 u1 = *reinterpret_cast<const f32x4*>(xg + 5 * (size_t)HW);
        f32x4 u2 = *reinterpret_cast<const f32x4*>(xg + 6 * (size_t)HW);
        f32x4 u3 = *reinterpret_cast<const f32x4*>(xg + 7 * (size_t)HW);
        #pragma unroll
        for (int j = 0; j < 4; ++j) {
            int px = px0 + j;
            uint2 pk = {cvtpk(-2.f * u0[j], -2.f * u1[j]),
                        cvtpk(-2.f * u2[j], -2.f * u3[j])};
            int byte = px * 128 + ((dh ^ ((px >> 1) & 7)) << 4) + 8;
            *reinterpret_cast<uint2*>(xc + byte) = pk;
        }
        #pragma unroll
        for (int j = 0; j < 4; ++j) {
            x2 = fmaf(u0[j], u0[j], x2); x2 = fmaf(u1[j], u1[j], x2);
            x2 = fmaf(u2[j], u2[j], x2); x2 = fmaf(u3[j], u3[j], x2);
        }
        #pragma unroll
        for (int off = 32; off > 0; off >>= 1) x2 += __shfl_down(x2, off, 64);
        if (lane == 0) wsum[w] = x2;
    }

    // ---- A-frags (after staging: live ranges don't overlap). PIN in VGPRs.
    short8v A0[4], A1[4];
    #pragma unroll
    for (int q = 0; q < 4; ++q) {
        int code = w * 64 + q * 16 + r15;
        const f32x4* ea = reinterpret_cast<const f32x4*>(emb + (size_t)code * D + g * 8);
        const f32x4* eh = reinterpret_cast<const f32x4*>(emb + (size_t)code * D + 32 + g * 8);
        f32x4 a0 = ea[0], a1 = ea[1], h0 = eh[0], h1 = eh[1];
        uint4v pa = {cvtpk(a0[0], a0[1]), cvtpk(a0[2], a0[3]),
                     cvtpk(a1[0], a1[1]), cvtpk(a1[2], a1[3])};
        uint4v ph = {cvtpk(h0[0], h0[1]), cvtpk(h0[2], h0[3]),
                     cvtpk(h1[0], h1[1]), cvtpk(h1[2], h1[3])};
        A0[q] = __builtin_bit_cast(short8v, pa);
        A1[q] = __builtin_bit_cast(short8v, ph);
        asm volatile("" : "+v"(A0[q]), "+v"(A1[q]));   // opaque def: no remat
    }

    if (t < PXT) kred[t] = 0xFFFFFFFFu;
    __syncthreads();                             // xbf + kred-init visible

    // ---- k-loop: wave scans 16 pixel-tiles vs its 64 codes; LDS atomicMin.
    const unsigned cb = (unsigned)(w * 64 + g * 4);   // bits disjoint from q*16+el
    const char* xr = reinterpret_cast<const char*>(xbf);
    #pragma unroll 4
    for (int pt = 0; pt < 16; ++pt) {
        const int P = pt * 16 + r15;
        const int sP = (P >> 1) & 7;
        short8v b0 = *reinterpret_cast<const short8v*>(xr + P * 128 + ((g ^ sP) << 4));
        short8v b1 = *reinterpret_cast<const short8v*>(xr + P * 128 + (((g + 4) ^ sP) << 4));
        unsigned tb[4];
        #pragma unroll
        for (int q = 0; q < 4; ++q) {
            f32x4 c = {16.f, 16.f, 16.f, 16.f};  // uniform bias => score' > 0
            c = __builtin_amdgcn_mfma_f32_16x16x32_bf16(A0[q], b0, c, 0, 0, 0);
            c = __builtin_amdgcn_mfma_f32_16x16x32_bf16(A1[q], b1, c, 0, 0, 0);
            unsigned k0 = (__builtin_bit_cast(unsigned, c[0]) & 0xFFFFFE00u) | (unsigned)(q * 16 + 0);
            unsigned k1 = (__builtin_bit_cast(unsigned, c[1]) & 0xFFFFFE00u) | (unsigned)(q * 16 + 1);
            unsigned k2 = (__builtin_bit_cast(unsigned, c[2]) & 0xFFFFFE00u) | (unsigned)(q * 16 + 2);
            unsigned k3 = (__builtin_bit_cast(unsigned, c[3]) & 0xFFFFFE00u) | (unsigned)(q * 16 + 3);
            tb[q] = umin32(umin32(k0, k1), umin32(k2, k3));   // tree, depth 2
        }
        unsigned best = umin32(umin32(tb[0], tb[1]), umin32(tb[2], tb[3])) | cb;
        best = umin32(best, (unsigned)__shfl_xor((int)best, 16, 64));
        best = umin32(best, (unsigned)__shfl_xor((int)best, 32, 64));
        if (g == 0) atomicMin(&kred[P], best);   // 16 distinct addrs, no conflict
    }
    __syncthreads();                             // all atomics done

    // ---- per-px: write inds (u16, contiguous 512B/block) + loss score part.
    if (t < PXT) {
        unsigned key = kred[t];
        ginds[tile * PXT + t] = (unsigned short)(key & 511u);
        float sq = __builtin_bit_cast(float, key & 0xFFFFFE00u) - 16.0f;
        #pragma unroll
        for (int off = 32; off > 0; off >>= 1) sq += __shfl_down(sq, off, 64);
        if (lane == 0) ssum[t >> 6] = sq;
    }
    __syncthreads();
    if (t == 0) {
        float p = ssum[0] + ssum[1] + ssum[2] + ssum[3];
        #pragma unroll
        for (int i = 0; i < 8; ++i) p += wsum[i];
        partials[tile] = p;                      // sum_px (||x||^2 + best score)
    }
}

// ---- K2: LINEAR-write scatter. Block = (b, 8-d-group): writes 128KB of
// out[b][d0..d0+8][*] fully contiguously (fill-kernel pattern). 256+1 blocks.
__global__ __launch_bounds__(512, 4) void vq_scatter(const float* __restrict__ emb,
                                                     const unsigned short* __restrict__ ginds,
                                                     const float* __restrict__ partials,
                                                     float* __restrict__ out) {
    const int blk = blockIdx.x;
    const int t   = threadIdx.x;

    if (blk == 256) {                            // finalize: reduce 512 partials
        __shared__ float s8[8];
        float v = partials[t];
        #pragma unroll
        for (int off = 32; off > 0; off >>= 1) v += __shfl_down(v, off, 64);
        if ((t & 63) == 0) s8[t >> 6] = v;
        __syncthreads();
        if (t == 0) {
            float tot = 0.f;
            #pragma unroll
            for (int i = 0; i < 8; ++i) tot += s8[i];
            out[NELEM] = 1.25f * tot / (float)NELEM;   // beta*commit + embed
        }
        return;
    }

    const int b   = blk >> 3;                    // 32 images
    const int d0  = (blk & 7) * 8;               // 8 d-rows per block
    const int pxA = (t & 511) * 4;               // group A: px [0, 2048)
    const int pxB = 2048 + pxA;                  // group B: px [2048, 4096)

    // ---- inds for this thread's 8 px (coalesced u16x4 loads, L2-resident).
    unsigned long long ivA =
        *reinterpret_cast<const unsigned long long*>(&ginds[(size_t)b * HW + pxA]);
    unsigned long long ivB =
        *reinterpret_cast<const unsigned long long*>(&ginds[(size_t)b * HW + pxB]);

    // ---- gather emb 8-d slices for 8 px (L2-hot, 16 x b128).
    f32x4 qAlo[4], qAhi[4], qBlo[4], qBhi[4];
    #pragma unroll
    for (int j = 0; j < 4; ++j) {
        const f32x4* erA = reinterpret_cast<const f32x4*>(
            emb + (size_t)((ivA >> (16 * j)) & 511u) * D + d0);
        const f32x4* erB = reinterpret_cast<const f32x4*>(
            emb + (size_t)((ivB >> (16 * j)) & 511u) * D + d0);
        qAlo[j] = erA[0]; qAhi[j] = erA[1];
        qBlo[j] = erB[0]; qBhi[j] = erB[1];
    }

    // ---- stores: block's 16 store-slots tile out[b][d0..d0+8][0..4096)
    // = 128KB fully linear. Each wave-instr is 1KB; consecutive waves cover
    // consecutive 1KB chunks of the same row; rows adjacent in memory.
    float* og = out + ((size_t)b * D + d0) * HW;
    #pragma unroll
    for (int i = 0; i < 4; ++i) {
        f32x4 oA  = {qAlo[0][i], qAlo[1][i], qAlo[2][i], qAlo[3][i]};
        f32x4 oB  = {qBlo[0][i], qBlo[1][i], qBlo[2][i], qBlo[3][i]};
        f32x4 oA2 = {qAhi[0][i], qAhi[1][i], qAhi[2][i], qAhi[3][i]};
        f32x4 oB2 = {qBhi[0][i], qBhi[1][i], qBhi[2][i], qBhi[3][i]};
        __builtin_nontemporal_store(oA,  reinterpret_cast<f32x4*>(og + (size_t)i * HW + pxA));
        __builtin_nontemporal_store(oB,  reinterpret_cast<f32x4*>(og + (size_t)i * HW + pxB));
        __builtin_nontemporal_store(oA2, reinterpret_cast<f32x4*>(og + (size_t)(i + 4) * HW + pxA));
        __builtin_nontemporal_store(oB2, reinterpret_cast<f32x4*>(og + (size_t)(i + 4) * HW + pxB));
    }
}

extern "C" void kernel_launch(void* const* d_in, const int* in_sizes, int n_in,
                              void* d_out, int out_size, void* d_ws, size_t ws_size,
                              hipStream_t stream) {
    const float* latents = (const float*)d_in[0];
    const float* emb     = (const float*)d_in[1];
    float* out = (float*)d_out;

    float*          part  = (float*)d_ws;                           // 512 floats
    unsigned short* ginds = (unsigned short*)((char*)d_ws + 4096);  // 256KB

    vq_argmin<<<NBLK, 512, 0, stream>>>(latents, emb, ginds, part);
    vq_scatter<<<257, 512, 0, stream>>>(emb, ginds, part, out);
}

// Round 19
// 25.287 us; speedup vs baseline: 1.1773x; 1.1773x over previous
//
#include <hip/hip_runtime.h>

// VQ codebook search via bf16 MFMA — wide-tile (256px) 1KB-contiguous-I/O.
// latents: [32, 64, 64, 64] = [b, d, h, w] fp32
// emb:     [512, 64] fp32
// out:     8388608 floats quantized (b,d,h,w) + 1 float vq_loss
//
// BEST-MEASURED CONFIG (R14, 25.0us): 512 blocks x 512 thr, 256 px/block,
// 2 blocks/CU. Thread owns 4px x 8d => every global load/store instruction
// is 1KB fully contiguous; per-block DRAM row segments 1KB. R15-R18 tested
// bigger granules / more occupancy / split kernels / linear writes — all
// neutral or worse; this fused shape is the optimum.
// A = bf16(E) in VGPRs, PINNED via opaque asm def (stops rematerialization —
//   R8/R9 3x bug: allocator reloaded A from global inside the k-loop).
// score'[n,k] = 16 - 2 x.e (e2 dropped: |e2| <= 2.4e-4 << accepted bf16
//   score-noise). key = (float_bits(score') & ~511) | code; min-tree;
//   cross-wave combine via LDS atomicMin (order-independent => deterministic).
// loss = sum x^2 (fp32) + sum(key_score - 16); 512 partials -> finalize.
//
// ws layout: [0..512) float partials.

typedef short  short8v __attribute__((ext_vector_type(8)));
typedef float  f32x4   __attribute__((ext_vector_type(4)));
typedef unsigned int uint4v __attribute__((ext_vector_type(4)));

constexpr int K = 512;
constexpr int D = 64;
constexpr int HW = 4096;
constexpr int NPIX = 32 * HW;
constexpr long long NELEM = (long long)NPIX * D;
constexpr int PXT = 256;                  // pixels per block
constexpr int NBLK = NPIX / PXT;          // 512 blocks

__device__ inline unsigned cvtpk(float lo, float hi) {   // 2x f32 -> packed bf16 (RNE)
    unsigned r;
    asm("v_cvt_pk_bf16_f32 %0, %1, %2" : "=v"(r) : "v"(lo), "v"(hi));
    return r;
}
__device__ inline unsigned umin32(unsigned a, unsigned b) { return a < b ? a : b; }

// ---- main kernel ----
__global__ __launch_bounds__(512, 4) void vq_main(const float* __restrict__ latents,
                                                  const float* __restrict__ emb,
                                                  float* __restrict__ out,
                                                  float* __restrict__ partials) {
    __shared__ unsigned short xbf[PXT * D];      // 32KB bf16(-2x) px-major, swizzled
    __shared__ unsigned int   kred[PXT];         // 1KB block-wide best keys
    __shared__ unsigned short inds[PXT];         // 512B chosen codes
    __shared__ float          wsum[8], ssum[4];

    const int t    = threadIdx.x;
    const int lane = t & 63, w = t >> 6;         // 8 waves
    const int r15  = lane & 15, g = lane >> 4;
    const int tile = blockIdx.x;
    const int b    = tile >> 4, hw0 = (tile & 15) * PXT;
    const int px0  = (t & 63) * 4;               // 4 px per thread
    const int d0   = (t >> 6) * 8;               // 8 d per thread (= wave id * 8)

    // ---- stage x: 8 loads, each instruction 1KB contiguous (one d-row/wave).
    const float* xg = latents + ((size_t)b * D + d0) * HW + hw0 + px0;
    f32x4 v[8];
    #pragma unroll
    for (int i = 0; i < 8; ++i)
        v[i] = *reinterpret_cast<const f32x4*>(xg + (size_t)i * HW);

    // ---- A-frags once per block: fp32 emb (L2-hot) -> cvt_pk -> PIN.
    short8v A0[4], A1[4];
    #pragma unroll
    for (int q = 0; q < 4; ++q) {
        int code = w * 64 + q * 16 + r15;
        const f32x4* ea = reinterpret_cast<const f32x4*>(emb + (size_t)code * D + g * 8);
        const f32x4* eh = reinterpret_cast<const f32x4*>(emb + (size_t)code * D + 32 + g * 8);
        f32x4 a0 = ea[0], a1 = ea[1], h0 = eh[0], h1 = eh[1];
        uint4v pa = {cvtpk(a0[0], a0[1]), cvtpk(a0[2], a0[3]),
                     cvtpk(a1[0], a1[1]), cvtpk(a1[2], a1[3])};
        uint4v ph = {cvtpk(h0[0], h0[1]), cvtpk(h0[2], h0[3]),
                     cvtpk(h1[0], h1[1]), cvtpk(h1[2], h1[3])};
        A0[q] = __builtin_bit_cast(short8v, pa);
        A1[q] = __builtin_bit_cast(short8v, ph);
        asm volatile("" : "+v"(A0[q]), "+v"(A1[q]));   // opaque def: no remat
    }

    // ---- init kred; pack x -> bf16(-2x): per px, the 8 d-values form ONE
    // swizzled 16B chunk -> 4x ds_write_b128. x^2 accumulated fp32-exact.
    if (t < PXT) kred[t] = 0xFFFFFFFFu;
    float x2 = 0.f;
    {
        char* xc = reinterpret_cast<char*>(xbf);
        #pragma unroll
        for (int j = 0; j < 4; ++j) {
            int px = px0 + j;
            uint4v pk = {cvtpk(-2.f * v[0][j], -2.f * v[1][j]),
                         cvtpk(-2.f * v[2][j], -2.f * v[3][j]),
                         cvtpk(-2.f * v[4][j], -2.f * v[5][j]),
                         cvtpk(-2.f * v[6][j], -2.f * v[7][j])};
            int byte = px * 128 + (((d0 >> 3) ^ ((px >> 1) & 7)) << 4);
            *reinterpret_cast<uint4v*>(xc + byte) = pk;
        }
        #pragma unroll
        for (int i = 0; i < 8; ++i)
            #pragma unroll
            for (int j = 0; j < 4; ++j) x2 = fmaf(v[i][j], v[i][j], x2);
        #pragma unroll
        for (int off = 32; off > 0; off >>= 1) x2 += __shfl_down(x2, off, 64);
        if (lane == 0) wsum[w] = x2;
    }
    __syncthreads();                             // xbf + kred-init visible

    // ---- k-loop: wave scans 16 pixel-tiles vs its 64 codes; LDS atomicMin.
    const unsigned cb = (unsigned)(w * 64 + g * 4);   // bits disjoint from q*16+el
    const char* xc = reinterpret_cast<const char*>(xbf);
    #pragma unroll 4
    for (int pt = 0; pt < 16; ++pt) {
        const int P = pt * 16 + r15;
        const int sP = (P >> 1) & 7;
        short8v b0 = *reinterpret_cast<const short8v*>(xc + P * 128 + ((g ^ sP) << 4));
        short8v b1 = *reinterpret_cast<const short8v*>(xc + P * 128 + (((g + 4) ^ sP) << 4));
        unsigned tb[4];
        #pragma unroll
        for (int q = 0; q < 4; ++q) {
            f32x4 c = {16.f, 16.f, 16.f, 16.f};  // uniform bias => score' > 0
            c = __builtin_amdgcn_mfma_f32_16x16x32_bf16(A0[q], b0, c, 0, 0, 0);
            c = __builtin_amdgcn_mfma_f32_16x16x32_bf16(A1[q], b1, c, 0, 0, 0);
            unsigned k0 = (__builtin_bit_cast(unsigned, c[0]) & 0xFFFFFE00u) | (unsigned)(q * 16 + 0);
            unsigned k1 = (__builtin_bit_cast(unsigned, c[1]) & 0xFFFFFE00u) | (unsigned)(q * 16 + 1);
            unsigned k2 = (__builtin_bit_cast(unsigned, c[2]) & 0xFFFFFE00u) | (unsigned)(q * 16 + 2);
            unsigned k3 = (__builtin_bit_cast(unsigned, c[3]) & 0xFFFFFE00u) | (unsigned)(q * 16 + 3);
            tb[q] = umin32(umin32(k0, k1), umin32(k2, k3));   // tree, depth 2
        }
        unsigned best = umin32(umin32(tb[0], tb[1]), umin32(tb[2], tb[3])) | cb;
        best = umin32(best, (unsigned)__shfl_xor((int)best, 16, 64));
        best = umin32(best, (unsigned)__shfl_xor((int)best, 32, 64));
        if (g == 0) atomicMin(&kred[P], best);   // 16 distinct addrs, no conflict
    }
    __syncthreads();                             // all atomics done

    // ---- per-px: extract index + score part of the loss.
    if (t < PXT) {
        unsigned key = kred[t];
        inds[t] = (unsigned short)(key & 511u);
        float sq = __builtin_bit_cast(float, key & 0xFFFFFE00u) - 16.0f;
        #pragma unroll
        for (int off = 32; off > 0; off >>= 1) sq += __shfl_down(sq, off, 64);
        if (lane == 0) ssum[t >> 6] = sq;
    }
    __syncthreads();                             // inds + ssum visible

    // ---- epilogue: gather emb rows (L2-hot), transpose, nontemporal 1KB
    // d-major stores (one d-row per wave per instruction).
    unsigned long long iv = *reinterpret_cast<const unsigned long long*>(&inds[px0]);
    f32x4 qlo[4], qhi[4];
    #pragma unroll
    for (int j = 0; j < 4; ++j) {
        const f32x4* er = reinterpret_cast<const f32x4*>(
            emb + (size_t)((iv >> (16 * j)) & 511u) * D + d0);
        qlo[j] = er[0];                          // d0..d0+3
        qhi[j] = er[1];                          // d0+4..d0+7
    }
    float* og = out + ((size_t)b * D + d0) * HW + hw0 + px0;
    #pragma unroll
    for (int i = 0; i < 4; ++i) {
        f32x4 o  = {qlo[0][i], qlo[1][i], qlo[2][i], qlo[3][i]};
        f32x4 o2 = {qhi[0][i], qhi[1][i], qhi[2][i], qhi[3][i]};
        __builtin_nontemporal_store(o,  reinterpret_cast<f32x4*>(og + (size_t)i * HW));
        __builtin_nontemporal_store(o2, reinterpret_cast<f32x4*>(og + (size_t)(i + 4) * HW));
    }

    // ---- block loss partial.
    if (t == 0) {
        float p = ssum[0] + ssum[1] + ssum[2] + ssum[3];
        #pragma unroll
        for (int i = 0; i < 8; ++i) p += wsum[i];
        partials[blockIdx.x] = p;                // sum_px (||x||^2 + best score)
    }
}

__global__ __launch_bounds__(512) void vq_finalize(const float* __restrict__ partials,
                                                   float* __restrict__ out_loss) {
    int t = threadIdx.x;
    float v = partials[t];                       // 512 partials, one block
    #pragma unroll
    for (int off = 32; off > 0; off >>= 1) v += __shfl_down(v, off, 64);
    __shared__ float s8[8];
    if ((t & 63) == 0) s8[t >> 6] = v;
    __syncthreads();
    if (t == 0) {
        float tot = 0.f;
        #pragma unroll
        for (int i = 0; i < 8; ++i) tot += s8[i];
        out_loss[0] = 1.25f * tot / (float)NELEM;   // beta*commit + embed
    }
}

extern "C" void kernel_launch(void* const* d_in, const int* in_sizes, int n_in,
                              void* d_out, int out_size, void* d_ws, size_t ws_size,
                              hipStream_t stream) {
    const float* latents = (const float*)d_in[0];
    const float* emb     = (const float*)d_in[1];
    float* out  = (float*)d_out;
    float* part = (float*)d_ws;                  // 512 floats, rewritten every call

    vq_main<<<NBLK, 512, 0, stream>>>(latents, emb, out, part);
    vq_finalize<<<1, 512, 0, stream>>>(part, out + NELEM);
}